// Round 3
// baseline (552.156 us; speedup 1.0000x reference)
//
#include <hip/hip_runtime.h>
#include <math.h>

#define KM 16
#define KS 64
#define TWO_PI_F 6.283185307179586477f

__global__ __launch_bounds__(256)
void mobius_spline_kernel(const float* __restrict__ r_in,
                          const float* __restrict__ z_in,
                          const float* __restrict__ theta_w,
                          const float* __restrict__ theta_h,
                          const float* __restrict__ theta_d,
                          const float* __restrict__ W1,
                          const float* __restrict__ b1,
                          const float* __restrict__ W2,
                          const float* __restrict__ b2,
                          const float* __restrict__ W3,
                          const float* __restrict__ b3,
                          float* __restrict__ out,
                          int n)
{
    // all LDS reads in the hot loop are wave-uniform (broadcast) -> no bank conflicts
    __shared__ __align__(16) float sW2T[64 * 64];   // W2 transposed: sW2T[i*64+j] = W2[j][i]
    __shared__ __align__(16) float sW3[64 * 48];    // row-major, as stored
    __shared__ __align__(16) float sW1b1[128];      // interleaved (W1[i], b1[i])
    __shared__ float sb2[64];
    __shared__ float sb3[48];
    __shared__ float sxk[KS + 1], syk[KS + 1], sdk[KS + 1];
    __shared__ float stmp[2 * KS];

    const int tid = threadIdx.x;

    for (int i = tid; i < 64 * 64; i += 256) {
        const int row = i >> 6, col = i & 63;       // sW2T[row][col] = W2[col][row]
        sW2T[i] = W2[col * 64 + row];               // W2 (16KB) stays L2-resident across blocks
    }
    for (int i = tid; i < 64 * 48; i += 256) sW3[i] = W3[i];

    if (tid < 64) {  // exactly wave 0: spline tables + small params
        sW1b1[2 * tid]     = W1[tid];
        sW1b1[2 * tid + 1] = b1[tid];
        sb2[tid] = b2[tid];
        if (tid < 48) sb3[tid] = b3[tid];

        float vw = theta_w[tid];
        float vh = theta_h[tid];
        float mw = vw, mh = vh;
        #pragma unroll
        for (int off = 32; off > 0; off >>= 1) {
            mw = fmaxf(mw, __shfl_xor(mw, off));
            mh = fmaxf(mh, __shfl_xor(mh, off));
        }
        const float ew = expf(vw - mw);
        const float eh = expf(vh - mh);
        float sumw = ew, sumh = eh;
        #pragma unroll
        for (int off = 32; off > 0; off >>= 1) {
            sumw += __shfl_xor(sumw, off);
            sumh += __shfl_xor(sumh, off);
        }
        stmp[tid]      = ew / sumw * 2.0f;   // width
        stmp[KS + tid] = eh / sumh * 2.0f;   // height

        if (tid < KS - 1) {
            const float x = theta_d[tid];
            const float sp = (x > 20.0f) ? x : log1pf(expf(x));
            sdk[1 + tid] = sp + 0.001f;
        }
        if (tid == 0) { sdk[0] = 1.0f; sdk[KS] = 1.0f; }
    }
    __syncthreads();
    if (tid == 0) {  // sequential cumsum matches jnp.cumsum accumulation order
        float cx = -1.0f, cy = -1.0f;
        sxk[0] = -1.0f; syk[0] = -1.0f;
        #pragma unroll 1
        for (int i = 0; i < KS; i++) {
            cx += stmp[i];
            cy += stmp[KS + i];
            sxk[i + 1] = cx;
            syk[i + 1] = cy;
        }
    }
    __syncthreads();

    const int idx = blockIdx.x * 256 + tid;
    if (idx >= n) return;

    const float rv = r_in[idx];
    const float zz = z_in[idx];

    // ---------------- spline ----------------
    // searchsorted side='left': first i with sxk[i] >= rv
    int lo = 0, hi = KS + 1;
    while (lo < hi) {
        const int mid = (lo + hi) >> 1;
        if (sxk[mid] < rv) lo = mid + 1; else hi = mid;
    }
    int k = lo;
    k = (k == 0) ? 1 : k;
    k = (k == KS + 1) ? KS : k;
    k -= 1;
    const float x_k = sxk[k], x_nk = sxk[k + 1];
    const float y_k = syk[k], y_nk = syk[k + 1];
    const float d_k = sdk[k], d_nk = sdk[k + 1];
    const float dxk = x_nk - x_k;
    const float s_k = (y_nk - y_k) / dxk;
    const float eps = (rv - x_k) / dxk;
    const float ome = 1.0f - eps;
    const float den = s_k + (d_nk + d_k - 2.0f * s_k) * eps * ome;
    const float tr  = y_k + (y_nk - y_k) * (s_k * eps * eps + d_k * eps * ome) / den;
    const float dtr = s_k * s_k * (d_nk * eps * eps + 2.0f * s_k * eps * ome + d_k * ome * ome)
                      / (den * den);

    // ---------------- MLP ----------------
    float h1[64];
    #pragma unroll
    for (int i = 0; i < 64; i++) {
        const float2 wb = ((const float2*)sW1b1)[i];
        h1[i] = fmaxf(fmaf(rv, wb.x, wb.y), 0.0f);
    }

    float theta[48];
    #pragma unroll
    for (int kk = 0; kk < 48; kk++) theta[kk] = sb3[kk];

    #pragma unroll 4
    for (int i = 0; i < 64; i++) {
        // h2_i = relu( dot(h1, W2[:,i]) + b2_i ), 4 partial accs for ILP
        float a0 = sb2[i], a1 = 0.0f, a2 = 0.0f, a3 = 0.0f;
        const float4* w2r = (const float4*)&sW2T[i * 64];
        #pragma unroll
        for (int j4 = 0; j4 < 16; j4++) {
            const float4 w = w2r[j4];
            a0 = fmaf(h1[4 * j4 + 0], w.x, a0);
            a1 = fmaf(h1[4 * j4 + 1], w.y, a1);
            a2 = fmaf(h1[4 * j4 + 2], w.z, a2);
            a3 = fmaf(h1[4 * j4 + 3], w.w, a3);
        }
        const float hv = fmaxf((a0 + a1) + (a2 + a3), 0.0f);
        const float4* w3r = (const float4*)&sW3[i * 48];
        #pragma unroll
        for (int k4 = 0; k4 < 12; k4++) {
            const float4 w = w3r[k4];
            theta[4 * k4 + 0] = fmaf(hv, w.x, theta[4 * k4 + 0]);
            theta[4 * k4 + 1] = fmaf(hv, w.y, theta[4 * k4 + 1]);
            theta[4 * k4 + 2] = fmaf(hv, w.z, theta[4 * k4 + 2]);
            theta[4 * k4 + 3] = fmaf(hv, w.w, theta[4 * k4 + 3]);
        }
    }

    // ---------------- mobius ----------------
    float mx = theta[0];
    #pragma unroll
    for (int i = 1; i < KM; i++) mx = fmaxf(mx, theta[i]);

    float cz, sz2;
    sincosf(zz, &sz2, &cz);

    float wsum = 0.0f, tsum = 0.0f, dsum = 0.0f;
    #pragma unroll
    for (int q = 0; q < KM; q++) {
        const float rwx = theta[KM + 2 * q];
        const float rwy = theta[KM + 2 * q + 1];
        const float nrm = sqrtf(rwx * rwx + rwy * rwy);
        const float scl = 0.99f / (1.0f + nrm);
        const float wx = scl * rwx, wy = scl * rwy;
        const float wn2 = wx * wx + wy * wy;
        const float omw = 1.0f - wn2;
        // h_map(zv, w)
        const float dzx = cz - wx, dzy = sz2 - wy;
        const float dn2z = dzx * dzx + dzy * dzy;
        const float cf = omw / dn2z;
        const float hzx = cf * dzx - wx;
        const float hzy = cf * dzy - wy;
        // h_map((1,0), w)
        const float d0x = 1.0f - wx, d0y = -wy;
        const float dn20 = d0x * d0x + d0y * d0y;
        const float c0 = omw / dn20;
        const float h0x = c0 * d0x - wx;
        const float h0y = c0 * d0y - wy;
        const float rad = atan2f(hzy, hzx);
        const float shf = atan2f(h0y, h0x);
        float tx = rad - shf;
        tx = (tx >= 0.0f) ? tx : tx + TWO_PI_F;
        const float ew = expf(theta[q] - mx);
        wsum += ew;
        tsum += ew * tx;
        // |dh| = cf exactly: dh = cf*(dz - 2u(u.dz)) is a reflection of unit dz
        dsum += ew * cf;
    }
    const float inv = 1.0f / wsum;
    const float tz  = tsum * inv;
    const float dtz = dsum * inv;
    const float ldj = logf(dtr) + logf(dtz);

    out[idx]         = tr;
    out[n + idx]     = tz;
    out[2 * n + idx] = ldj;
}

extern "C" void kernel_launch(void* const* d_in, const int* in_sizes, int n_in,
                              void* d_out, int out_size, void* d_ws, size_t ws_size,
                              hipStream_t stream) {
    const int n = in_sizes[0];  // 1,000,000
    const int blocks = (n + 255) / 256;
    hipLaunchKernelGGL(mobius_spline_kernel, dim3(blocks), dim3(256), 0, stream,
                       (const float*)d_in[0], (const float*)d_in[1],
                       (const float*)d_in[2], (const float*)d_in[3],
                       (const float*)d_in[4], (const float*)d_in[5],
                       (const float*)d_in[6], (const float*)d_in[7],
                       (const float*)d_in[8], (const float*)d_in[9],
                       (const float*)d_in[10],
                       (float*)d_out, n);
}

// Round 4
// 351.313 us; speedup vs baseline: 1.5717x; 1.5717x over previous
//
#include <hip/hip_runtime.h>
#include <math.h>

#define KM 16
#define KS 64
#define TWO_PI_F 6.283185307179586477f

__global__ __launch_bounds__(256)
void mobius_spline_kernel(const float* __restrict__ r_in,
                          const float* __restrict__ z_in,
                          const float* __restrict__ theta_w,
                          const float* __restrict__ theta_h,
                          const float* __restrict__ theta_d,
                          const float* __restrict__ W1,
                          const float* __restrict__ b1,
                          const float* __restrict__ W2,
                          const float* __restrict__ b2,
                          const float* __restrict__ W3,
                          const float* __restrict__ b3,
                          float* __restrict__ out,
                          int n)
{
    // LDS only for the spline tables (per-thread non-uniform index).
    // All MLP weights are read straight from global with WAVE-UNIFORM indices
    // -> compiler emits s_load (scalar pipe + K$), zero LDS/VALU-pipe cost.
    __shared__ float sxk[KS + 1], syk[KS + 1], sdk[KS + 1];
    __shared__ float stmp[2 * KS];

    const int tid = threadIdx.x;

    if (tid < 64) {  // exactly wave 0: spline tables
        float vw = theta_w[tid];
        float vh = theta_h[tid];
        float mw = vw, mh = vh;
        #pragma unroll
        for (int off = 32; off > 0; off >>= 1) {
            mw = fmaxf(mw, __shfl_xor(mw, off));
            mh = fmaxf(mh, __shfl_xor(mh, off));
        }
        const float ew = expf(vw - mw);
        const float eh = expf(vh - mh);
        float sumw = ew, sumh = eh;
        #pragma unroll
        for (int off = 32; off > 0; off >>= 1) {
            sumw += __shfl_xor(sumw, off);
            sumh += __shfl_xor(sumh, off);
        }
        stmp[tid]      = ew / sumw * 2.0f;   // width
        stmp[KS + tid] = eh / sumh * 2.0f;   // height

        if (tid < KS - 1) {
            const float x = theta_d[tid];
            const float sp = (x > 20.0f) ? x : log1pf(expf(x));
            sdk[1 + tid] = sp + 0.001f;
        }
        if (tid == 0) { sdk[0] = 1.0f; sdk[KS] = 1.0f; }
    }
    __syncthreads();
    if (tid == 0) {  // sequential cumsum matches jnp.cumsum accumulation order
        float cx = -1.0f, cy = -1.0f;
        sxk[0] = -1.0f; syk[0] = -1.0f;
        #pragma unroll 1
        for (int i = 0; i < KS; i++) {
            cx += stmp[i];
            cy += stmp[KS + i];
            sxk[i + 1] = cx;
            syk[i + 1] = cy;
        }
    }
    __syncthreads();

    const int idx = blockIdx.x * 256 + tid;
    if (idx >= n) return;

    const float rv = r_in[idx];
    const float zz = z_in[idx];

    // ---------------- spline ----------------
    int lo = 0, hi = KS + 1;
    while (lo < hi) {
        const int mid = (lo + hi) >> 1;
        if (sxk[mid] < rv) lo = mid + 1; else hi = mid;
    }
    int k = lo;
    k = (k == 0) ? 1 : k;
    k = (k == KS + 1) ? KS : k;
    k -= 1;
    const float x_k = sxk[k], x_nk = sxk[k + 1];
    const float y_k = syk[k], y_nk = syk[k + 1];
    const float d_k = sdk[k], d_nk = sdk[k + 1];
    const float dxk = x_nk - x_k;
    const float s_k = (y_nk - y_k) / dxk;
    const float eps = (rv - x_k) / dxk;
    const float ome = 1.0f - eps;
    const float den = s_k + (d_nk + d_k - 2.0f * s_k) * eps * ome;
    const float tr  = y_k + (y_nk - y_k) * (s_k * eps * eps + d_k * eps * ome) / den;
    const float dtr = s_k * s_k * (d_nk * eps * eps + 2.0f * s_k * eps * ome + d_k * ome * ome)
                      / (den * den);

    // ---------------- MLP phase 1: h2 = relu(h1 @ W2 + b2) ----------------
    // Outer-product order: h1_j computed on the fly (never stored as array).
    float h2[64];
    #pragma unroll
    for (int i = 0; i < 64; i++) h2[i] = b2[i];          // uniform -> s_load

    #pragma unroll 2
    for (int j = 0; j < 64; j++) {
        const float h1j = fmaxf(fmaf(rv, W1[j], b1[j]), 0.0f);  // uniform s_loads
        const float* __restrict__ w2row = &W2[j * 64];          // row-major, natural
        #pragma unroll
        for (int i = 0; i < 64; i++)
            h2[i] = fmaf(h1j, w2row[i], h2[i]);                 // v_fmac v,s,v
    }
    #pragma unroll
    for (int i = 0; i < 64; i++) h2[i] = fmaxf(h2[i], 0.0f);

    // ---------------- MLP phase 2 + mobius, chunked to cap live registers ----
    // chunk 0: theta[0:16]  (softmax logits -> keep)
    float th0[16];
    #pragma unroll
    for (int q = 0; q < 16; q++) th0[q] = b3[q];
    #pragma unroll 2
    for (int i = 0; i < 64; i++) {
        const float hv = h2[i];
        const float* __restrict__ w3r = &W3[i * 48];
        #pragma unroll
        for (int q = 0; q < 16; q++) th0[q] = fmaf(hv, w3r[q], th0[q]);
    }
    float mx = th0[0];
    #pragma unroll
    for (int q = 1; q < 16; q++) mx = fmaxf(mx, th0[q]);

    float cz, sz2;
    sincosf(zz, &sz2, &cz);
    float wsum = 0.0f, tsum = 0.0f, dsum = 0.0f;

    // chunks 1,2: theta[16:32], theta[32:48] = w-pairs; consume immediately
    #pragma unroll 1
    for (int c = 1; c < 3; c++) {
        float acc[16];
        #pragma unroll
        for (int q = 0; q < 16; q++) acc[q] = b3[c * 16 + q];
        #pragma unroll 2
        for (int i = 0; i < 64; i++) {
            const float hv = h2[i];
            const float* __restrict__ w3r = &W3[i * 48 + c * 16];
            #pragma unroll
            for (int q = 0; q < 16; q++) acc[q] = fmaf(hv, w3r[q], acc[q]);
        }
        const int qbase = (c - 1) * 8;
        #pragma unroll
        for (int qq = 0; qq < 8; qq++) {
            const int q = qbase + qq;           // mobius term index, same order as ref
            const float rwx = acc[2 * qq];
            const float rwy = acc[2 * qq + 1];
            const float nrm = sqrtf(rwx * rwx + rwy * rwy);
            const float scl = 0.99f / (1.0f + nrm);
            const float wx = scl * rwx, wy = scl * rwy;
            const float wn2 = wx * wx + wy * wy;
            const float omw = 1.0f - wn2;
            // h_map(zv, w)
            const float dzx = cz - wx, dzy = sz2 - wy;
            const float dn2z = dzx * dzx + dzy * dzy;
            const float cf = omw / dn2z;
            const float hzx = cf * dzx - wx;
            const float hzy = cf * dzy - wy;
            // h_map((1,0), w)
            const float d0x = 1.0f - wx, d0y = -wy;
            const float dn20 = d0x * d0x + d0y * d0y;
            const float c0 = omw / dn20;
            const float h0x = c0 * d0x - wx;
            const float h0y = c0 * d0y - wy;
            const float rad = atan2f(hzy, hzx);
            const float shf = atan2f(h0y, h0x);
            float tx = rad - shf;
            tx = (tx >= 0.0f) ? tx : tx + TWO_PI_F;
            const float ew = expf(th0[q] - mx);
            wsum += ew;
            tsum += ew * tx;
            // |dh| = cf exactly: dh = cf*(dz - 2u(u.dz)) is a reflection of unit dz
            dsum += ew * cf;
        }
    }

    const float inv = 1.0f / wsum;
    const float tz  = tsum * inv;
    const float dtz = dsum * inv;
    const float ldj = logf(dtr) + logf(dtz);

    out[idx]         = tr;
    out[n + idx]     = tz;
    out[2 * n + idx] = ldj;
}

extern "C" void kernel_launch(void* const* d_in, const int* in_sizes, int n_in,
                              void* d_out, int out_size, void* d_ws, size_t ws_size,
                              hipStream_t stream) {
    const int n = in_sizes[0];  // 1,000,000
    const int blocks = (n + 255) / 256;
    hipLaunchKernelGGL(mobius_spline_kernel, dim3(blocks), dim3(256), 0, stream,
                       (const float*)d_in[0], (const float*)d_in[1],
                       (const float*)d_in[2], (const float*)d_in[3],
                       (const float*)d_in[4], (const float*)d_in[5],
                       (const float*)d_in[6], (const float*)d_in[7],
                       (const float*)d_in[8], (const float*)d_in[9],
                       (const float*)d_in[10],
                       (float*)d_out, n);
}